// Round 3
// baseline (13392.780 us; speedup 1.0000x reference)
//
#include <hip/hip_runtime.h>
#include <math.h>

// TopDownNet fp32 (threshold 2.2e-5 forbids bf16 MFMA). N=131072, K=10, H=256.
// R2 design: 1-wave blocks (fully independent samples -> ZERO barriers).
// Wave = 16 samples: lanes 0-31 own samples 0-7, lanes 32-63 own samples 8-15.
// Lane ll (=l&31) owns 8 weight cols {ll+32j} via column-shuffled weights so
// the global load stays 2x dwordx4/row; per row: 128 FMA-cyc vs ~2 broadcast
// LDS reads -> VALU-bound (R1 at TN=4 was LDS-pipe-bound at 75% VALU).
// Row stride 18 floats: write banks 18*ll mod 32 take 16 distinct values ->
// ~4-way b64 write conflicts (R1: 32-way).

constexpr int NH   = 256;
constexpr int NIN  = 14;
constexpr int KS   = 10;
constexpr int SPW  = 16;             // samples per wave
constexpr int SROW = 18;             // LDS row stride (floats)
constexpr int ABUF = NH * SROW;      // 4608 floats per activation buffer

// Column-shuffled weights/biases (rewritten every launch; capture-safe).
__device__ float g_M1[270 * 256], g_O1[270 * 256];
__device__ float g_M2[256 * 256], g_M3[256 * 256], g_O2[256 * 256];
__device__ float g_M1b[256], g_M2b[256], g_M3b[256];
__device__ float g_O1b[256], g_O2b[256], g_O3[256];

// g_W[i][8*ll + j] = W[i][ll + 32*j]
__global__ void shuffle_kernel(const float* __restrict__ M1w, const float* __restrict__ M2w,
                               const float* __restrict__ M3w, const float* __restrict__ O1w,
                               const float* __restrict__ O2w, const float* __restrict__ O3w,
                               const float* __restrict__ M1b, const float* __restrict__ M2b,
                               const float* __restrict__ M3b, const float* __restrict__ O1b,
                               const float* __restrict__ O2b) {
  const int c = threadIdx.x;           // 0..255 (dst col)
  const int i = blockIdx.x;            // 0..269 (row)
  const int s = (c >> 3) + 32 * (c & 7);
  g_M1[i * 256 + c] = M1w[i * 256 + s];
  g_O1[i * 256 + c] = O1w[i * 256 + s];
  if (i < 256) {
    g_M2[i * 256 + c] = M2w[i * 256 + s];
    g_M3[i * 256 + c] = M3w[i * 256 + s];
    g_O2[i * 256 + c] = O2w[i * 256 + s];
  }
  if (i == 0) {
    g_M1b[c] = M1b[s]; g_M2b[c] = M2b[s]; g_M3b[c] = M3b[s];
    g_O1b[c] = O1b[s]; g_O2b[c] = O2b[s]; g_O3[c]  = O3w[s];
  }
}

__device__ __forceinline__ void zero_acc(float acc[8][8]) {
#pragma unroll
  for (int s = 0; s < 8; ++s)
#pragma unroll
    for (int j = 0; j < 8; ++j) acc[s][j] = 0.f;
}

// acc[s][j] += sum_i X[i][s] * W'[i][8ll+j]   (X is lane-uniform per 32-group)
template <int ROWS>
__device__ __forceinline__ void gemm8(float acc[8][8],
                                      const float* __restrict__ X,   // sm base + 8*g
                                      const float* __restrict__ Wg,  // shuffled, at row0
                                      int ll) {
  const float4* __restrict__ Wp = reinterpret_cast<const float4*>(Wg) + 2 * ll;
#pragma unroll 2
  for (int i = 0; i < ROWS; ++i) {
    float4 w0 = Wp[i * 64];        // byte offsets i*1024 (+16) -> immediates
    float4 w1 = Wp[i * 64 + 1];
    float2 x0 = *reinterpret_cast<const float2*>(X + i * SROW);
    float2 x1 = *reinterpret_cast<const float2*>(X + i * SROW + 2);
    float2 x2 = *reinterpret_cast<const float2*>(X + i * SROW + 4);
    float2 x3 = *reinterpret_cast<const float2*>(X + i * SROW + 6);
    const float xs[8] = {x0.x, x0.y, x1.x, x1.y, x2.x, x2.y, x3.x, x3.y};
    const float wj[8] = {w0.x, w0.y, w0.z, w0.w, w1.x, w1.y, w1.z, w1.w};
#pragma unroll
    for (int s = 0; s < 8; ++s)
#pragma unroll
      for (int j = 0; j < 8; ++j)
        acc[s][j] = fmaf(xs[s], wj[j], acc[s][j]);
  }
}

// Y[(ll+32j)*SROW + s] = relu(acc[s][j] + b'[8ll+j]); Y = sm base + 8*g
__device__ __forceinline__ void write_relu8(float* __restrict__ Y,
                                            const float acc[8][8],
                                            const float* __restrict__ Bv, int ll) {
  float4 b0 = reinterpret_cast<const float4*>(Bv)[2 * ll];
  float4 b1 = reinterpret_cast<const float4*>(Bv)[2 * ll + 1];
  const float bb[8] = {b0.x, b0.y, b0.z, b0.w, b1.x, b1.y, b1.z, b1.w};
#pragma unroll
  for (int j = 0; j < 8; ++j) {
    float* yr = Y + (ll + 32 * j) * SROW;
#pragma unroll
    for (int m = 0; m < 4; ++m) {
      float2 v;
      v.x = fmaxf(acc[2 * m][j] + bb[j], 0.f);
      v.y = fmaxf(acc[2 * m + 1][j] + bb[j], 0.f);
      *reinterpret_cast<float2*>(yr + 2 * m) = v;  // b64, 8B-aligned (SROW even)
    }
  }
}

__global__ __launch_bounds__(64, 1) void topdown_kernel(
    const float* __restrict__ towers, const float* __restrict__ aggregate,
    const float* __restrict__ O3b_p, float* __restrict__ out) {
  __shared__ float sm[2 * ABUF + NIN * SROW];
  float* Abuf = sm;
  float* Bbuf = sm + ABUF;
  float* Tbuf = sm + 2 * ABUF;

  const int l  = threadIdx.x;
  const int ll = l & 31;
  const int g  = l >> 5;
  const int go = 8 * g;
  const int n0 = blockIdx.x * SPW;

  // init summary A[r][c] = aggregate[r], c = 0..15; lane l covers rows 4l..4l+3
  {
    float4 av = reinterpret_cast<const float4*>(aggregate)[l];
    const float ar[4] = {av.x, av.y, av.z, av.w};
#pragma unroll
    for (int j = 0; j < 4; ++j) {
      float* row = Abuf + (4 * l + j) * SROW;
#pragma unroll
      for (int c = 0; c < 16; c += 2)
        *reinterpret_cast<float2*>(row + c) = make_float2(ar[j], ar[j]);
    }
  }

  float prod[8];
#pragma unroll
  for (int s = 0; s < 8; ++s) prod[s] = 1.f;

  float acc[8][8];
  const float o3bias = O3b_p[0];

  for (int kk = 0; kk < KS; ++kk) {
    const int tbase = (KS - 1 - kk) * NIN;  // reference flips along K

    // gather tower slice into regs early (latency hidden behind O1 A-part)
    const int e0 = l, e1 = l + 64, e2 = l + 128, e3 = l + 192;
    float tv0 = towers[(n0 + (e0 & 15)) * (KS * NIN) + tbase + (e0 >> 4)];
    float tv1 = towers[(n0 + (e1 & 15)) * (KS * NIN) + tbase + (e1 >> 4)];
    float tv2 = towers[(n0 + (e2 & 15)) * (KS * NIN) + tbase + (e2 >> 4)];
    float tv3 = (e3 < NIN * SPW)
                    ? towers[(n0 + (e3 & 15)) * (KS * NIN) + tbase + (e3 >> 4)]
                    : 0.f;

    // ---- O1 (A part) : A,T -> B
    zero_acc(acc);
    gemm8<NH>(acc, Abuf + go, g_O1, ll);

    // stage tower (prev-step M1 T-reads precede these writes in program order)
    Tbuf[(e0 >> 4) * SROW + (e0 & 15)] = tv0;
    Tbuf[(e1 >> 4) * SROW + (e1 & 15)] = tv1;
    Tbuf[(e2 >> 4) * SROW + (e2 & 15)] = tv2;
    if (e3 < NIN * SPW) Tbuf[(e3 >> 4) * SROW + (e3 & 15)] = tv3;

    gemm8<NIN>(acc, Tbuf + go, g_O1 + NH * 256, ll);
    write_relu8(Bbuf + go, acc, g_O1b, ll);

    // ---- O2 + folded O3 + sigmoid + prod (registers + 32-lane butterfly)
    zero_acc(acc);
    gemm8<NH>(acc, Bbuf + go, g_O2, ll);
    {
      float4 b0 = reinterpret_cast<const float4*>(g_O2b)[2 * ll];
      float4 b1 = reinterpret_cast<const float4*>(g_O2b)[2 * ll + 1];
      float4 o0 = reinterpret_cast<const float4*>(g_O3)[2 * ll];
      float4 o1 = reinterpret_cast<const float4*>(g_O3)[2 * ll + 1];
      const float bb[8] = {b0.x, b0.y, b0.z, b0.w, b1.x, b1.y, b1.z, b1.w};
      const float oo[8] = {o0.x, o0.y, o0.z, o0.w, o1.x, o1.y, o1.z, o1.w};
#pragma unroll
      for (int s = 0; s < 8; ++s) {
        float t = 0.f;
#pragma unroll
        for (int j = 0; j < 8; ++j)
          t = fmaf(fmaxf(acc[s][j] + bb[j], 0.f), oo[j], t);
        t += __shfl_xor(t, 1);
        t += __shfl_xor(t, 2);
        t += __shfl_xor(t, 4);
        t += __shfl_xor(t, 8);
        t += __shfl_xor(t, 16);  // sum over the 32-lane group -> all 256 cols
        prod[s] *= 1.f / (1.f + expf(-(t + o3bias)));
      }
    }

    // ---- M1: A,T -> A  (all 256 row-reads precede writes; per-wave LDS in-order)
    zero_acc(acc);
    gemm8<NH>(acc, Abuf + go, g_M1, ll);
    gemm8<NIN>(acc, Tbuf + go, g_M1 + NH * 256, ll);
    write_relu8(Abuf + go, acc, g_M1b, ll);

    // ---- M2: A -> B
    zero_acc(acc);
    gemm8<NH>(acc, Abuf + go, g_M2, ll);
    write_relu8(Bbuf + go, acc, g_M2b, ll);

    // ---- M3: B -> A
    zero_acc(acc);
    gemm8<NH>(acc, Bbuf + go, g_M3, ll);
    write_relu8(Abuf + go, acc, g_M3b, ll);
  }

  // lane with ll==s writes sample 8g+s (prod identical across the 32-group)
#pragma unroll
  for (int s = 0; s < 8; ++s)
    if (ll == s) out[n0 + 8 * g + s] = prod[s];
}

extern "C" void kernel_launch(void* const* d_in, const int* in_sizes, int n_in,
                              void* d_out, int out_size, void* d_ws, size_t ws_size,
                              hipStream_t stream) {
  const float* towers    = (const float*)d_in[0];
  const float* aggregate = (const float*)d_in[1];
  const float* M1w = (const float*)d_in[2];
  const float* M1b = (const float*)d_in[3];
  const float* M2w = (const float*)d_in[4];
  const float* M2b = (const float*)d_in[5];
  const float* M3w = (const float*)d_in[6];
  const float* M3b = (const float*)d_in[7];
  const float* O1w = (const float*)d_in[8];
  const float* O1b = (const float*)d_in[9];
  const float* O2w = (const float*)d_in[10];
  const float* O2b = (const float*)d_in[11];
  const float* O3w = (const float*)d_in[12];
  const float* O3b = (const float*)d_in[13];
  float* out = (float*)d_out;

  shuffle_kernel<<<270, 256, 0, stream>>>(M1w, M2w, M3w, O1w, O2w, O3w,
                                          M1b, M2b, M3b, O1b, O2b);

  const int nblocks = out_size / SPW;  // 131072 / 16 = 8192
  topdown_kernel<<<nblocks, 64, 0, stream>>>(towers, aggregate, O3b, out);
}

// Round 4
// 9929.815 us; speedup vs baseline: 1.3487x; 1.3487x over previous
//
#include <hip/hip_runtime.h>
#include <math.h>

// TopDownNet fp32 (threshold 2.2e-5 forbids bf16 MFMA). N=131072, K=10, H=256.
// R4: ONE LDS activation buffer (in-place M-layers), h1 kept in registers,
// O2 consumes h1 via ds_bpermute broadcast -> 19.4 KB LDS/block ->
// 8 single-wave blocks/CU = 2 waves/SIMD (R3 failed at 1 wave/SIMD, VALU 46%).
// Wave = 16 samples: lanes 0-31 = samples 0-7, lanes 32-63 = samples 8-15.
// Lane ll (=l&31) owns cols {ll+32j, j=0..7} via column-shuffled weights
// (global loads stay 2x dwordx4/row with immediate-friendly addressing).
// O1+M1 fused in one pass over [A,T] (half the LDS reads, 2 FMA chains).

constexpr int NH   = 256;
constexpr int NIN  = 14;
constexpr int KS   = 10;
constexpr int SPW  = 16;           // samples per wave
constexpr int SROW = 18;           // LDS row stride: 2-way write aliasing (free)
constexpr int ABUF = NH * SROW;    // 4608 floats

// Column-shuffled weights/biases (rewritten every launch; capture-safe).
__device__ float g_M1[270 * 256], g_O1[270 * 256];
__device__ float g_M2[256 * 256], g_M3[256 * 256], g_O2[256 * 256];
__device__ float g_M1b[256], g_M2b[256], g_M3b[256];
__device__ float g_O1b[256], g_O2b[256], g_O3[256];

// g_W[i][8*ll + j] = W[i][ll + 32*j]
__global__ void shuffle_kernel(const float* __restrict__ M1w, const float* __restrict__ M2w,
                               const float* __restrict__ M3w, const float* __restrict__ O1w,
                               const float* __restrict__ O2w, const float* __restrict__ O3w,
                               const float* __restrict__ M1b, const float* __restrict__ M2b,
                               const float* __restrict__ M3b, const float* __restrict__ O1b,
                               const float* __restrict__ O2b) {
  const int c = threadIdx.x;          // dst col 0..255
  const int i = blockIdx.x;           // row 0..269
  const int s = (c >> 3) + 32 * (c & 7);
  g_M1[i * 256 + c] = M1w[i * 256 + s];
  g_O1[i * 256 + c] = O1w[i * 256 + s];
  if (i < 256) {
    g_M2[i * 256 + c] = M2w[i * 256 + s];
    g_M3[i * 256 + c] = M3w[i * 256 + s];
    g_O2[i * 256 + c] = O2w[i * 256 + s];
  }
  if (i == 0) {
    g_M1b[c] = M1b[s]; g_M2b[c] = M2b[s]; g_M3b[c] = M3b[s];
    g_O1b[c] = O1b[s]; g_O2b[c] = O2b[s]; g_O3[c]  = O3w[s];
  }
}

__device__ __forceinline__ void zero8(float a[8][8]) {
#pragma unroll
  for (int s = 0; s < 8; ++s)
#pragma unroll
    for (int j = 0; j < 8; ++j) a[s][j] = 0.f;
}

// Dual accumulate: accO += O^T x, accM += M^T x over ROWS input rows.
template <int ROWS>
__device__ __forceinline__ void gemm_fused(float accO[8][8], float accM[8][8],
                                           const float* __restrict__ X,   // group base
                                           const float* __restrict__ WO,
                                           const float* __restrict__ WM, int ll) {
  const float4* __restrict__ Op = reinterpret_cast<const float4*>(WO) + 2 * ll;
  const float4* __restrict__ Mp = reinterpret_cast<const float4*>(WM) + 2 * ll;
#pragma unroll 2
  for (int i = 0; i < ROWS; ++i) {
    float4 o0 = Op[i * 64], o1 = Op[i * 64 + 1];
    float4 m0 = Mp[i * 64], m1 = Mp[i * 64 + 1];
    float2 x0 = *reinterpret_cast<const float2*>(X + i * SROW);
    float2 x1 = *reinterpret_cast<const float2*>(X + i * SROW + 2);
    float2 x2 = *reinterpret_cast<const float2*>(X + i * SROW + 4);
    float2 x3 = *reinterpret_cast<const float2*>(X + i * SROW + 6);
    const float xs[8] = {x0.x, x0.y, x1.x, x1.y, x2.x, x2.y, x3.x, x3.y};
    const float wo[8] = {o0.x, o0.y, o0.z, o0.w, o1.x, o1.y, o1.z, o1.w};
    const float wm[8] = {m0.x, m0.y, m0.z, m0.w, m1.x, m1.y, m1.z, m1.w};
#pragma unroll
    for (int s = 0; s < 8; ++s)
#pragma unroll
      for (int j = 0; j < 8; ++j) {
        accO[s][j] = fmaf(xs[s], wo[j], accO[s][j]);
        accM[s][j] = fmaf(xs[s], wm[j], accM[s][j]);
      }
  }
}

// Single accumulate (M2, M3).
template <int ROWS>
__device__ __forceinline__ void gemm8(float acc[8][8],
                                      const float* __restrict__ X,
                                      const float* __restrict__ Wg, int ll) {
  const float4* __restrict__ Wp = reinterpret_cast<const float4*>(Wg) + 2 * ll;
#pragma unroll 2
  for (int i = 0; i < ROWS; ++i) {
    float4 w0 = Wp[i * 64], w1 = Wp[i * 64 + 1];
    float2 x0 = *reinterpret_cast<const float2*>(X + i * SROW);
    float2 x1 = *reinterpret_cast<const float2*>(X + i * SROW + 2);
    float2 x2 = *reinterpret_cast<const float2*>(X + i * SROW + 4);
    float2 x3 = *reinterpret_cast<const float2*>(X + i * SROW + 6);
    const float xs[8] = {x0.x, x0.y, x1.x, x1.y, x2.x, x2.y, x3.x, x3.y};
    const float wj[8] = {w0.x, w0.y, w0.z, w0.w, w1.x, w1.y, w1.z, w1.w};
#pragma unroll
    for (int s = 0; s < 8; ++s)
#pragma unroll
      for (int j = 0; j < 8; ++j)
        acc[s][j] = fmaf(xs[s], wj[j], acc[s][j]);
  }
}

// In-place: Y[(ll+32j)*SROW + 2m..] = relu(acc + b'); Y = buffer + 8*g
__device__ __forceinline__ void write_relu8(float* __restrict__ Y,
                                            const float acc[8][8],
                                            const float* __restrict__ Bv, int ll) {
  float4 b0 = reinterpret_cast<const float4*>(Bv)[2 * ll];
  float4 b1 = reinterpret_cast<const float4*>(Bv)[2 * ll + 1];
  const float bb[8] = {b0.x, b0.y, b0.z, b0.w, b1.x, b1.y, b1.z, b1.w};
#pragma unroll
  for (int j = 0; j < 8; ++j) {
    float* yr = Y + (ll + 32 * j) * SROW;
#pragma unroll
    for (int m = 0; m < 4; ++m) {
      float2 v;
      v.x = fmaxf(acc[2 * m][j] + bb[j], 0.f);
      v.y = fmaxf(acc[2 * m + 1][j] + bb[j], 0.f);
      *reinterpret_cast<float2*>(yr + 2 * m) = v;
    }
  }
}

__global__ __launch_bounds__(64, 2) void topdown_kernel(
    const float* __restrict__ towers, const float* __restrict__ aggregate,
    const float* __restrict__ O3b_p, float* __restrict__ out) {
  __shared__ float sm[ABUF + NIN * SROW];  // 19440 B -> 8 blocks/CU
  float* Abuf = sm;
  float* Tbuf = sm + ABUF;

  const int l  = threadIdx.x;
  const int ll = l & 31;
  const int g  = l >> 5;          // sample-group: lanes 0-31 -> samples 0-7
  const int go = 8 * g;
  const int n0 = blockIdx.x * SPW;
  const int bpbase = (l & 32) * 4;  // ds_bpermute byte base of own group

  // init A[r][c] = aggregate[r] for c=0..15; lane covers rows 4l..4l+3
  {
    float4 av = reinterpret_cast<const float4*>(aggregate)[l];
    const float ar[4] = {av.x, av.y, av.z, av.w};
#pragma unroll
    for (int j = 0; j < 4; ++j) {
      float* row = Abuf + (4 * l + j) * SROW;
#pragma unroll
      for (int c = 0; c < 16; c += 2)
        *reinterpret_cast<float2*>(row + c) = make_float2(ar[j], ar[j]);
    }
  }

  float prod[8];
#pragma unroll
  for (int s = 0; s < 8; ++s) prod[s] = 1.f;

  float accO[8][8], accM[8][8];
  const float o3bias = O3b_p[0];

  for (int kk = 0; kk < KS; ++kk) {
    const int tbase = (KS - 1 - kk) * NIN;  // reference flips along K

    // prefetch tower slice (16 samples x 14 feats = 224 vals)
    const int e0 = l, e1 = l + 64, e2 = l + 128, e3 = l + 192;
    float tv0 = towers[(n0 + (e0 & 15)) * (KS * NIN) + tbase + (e0 >> 4)];
    float tv1 = towers[(n0 + (e1 & 15)) * (KS * NIN) + tbase + (e1 >> 4)];
    float tv2 = towers[(n0 + (e2 & 15)) * (KS * NIN) + tbase + (e2 >> 4)];
    float tv3 = (e3 < NIN * SPW)
                    ? towers[(n0 + (e3 & 15)) * (KS * NIN) + tbase + (e3 >> 4)]
                    : 0.f;
    Tbuf[(e0 >> 4) * SROW + (e0 & 15)] = tv0;
    Tbuf[(e1 >> 4) * SROW + (e1 & 15)] = tv1;
    Tbuf[(e2 >> 4) * SROW + (e2 & 15)] = tv2;
    if (e3 < NIN * SPW) Tbuf[(e3 >> 4) * SROW + (e3 & 15)] = tv3;

    // ---- fused O1 + M1 over x = [A, T]
    zero8(accO); zero8(accM);
    gemm_fused<NH>(accO, accM, Abuf + go, g_O1, g_M1, ll);
    gemm_fused<NIN>(accO, accM, Tbuf + go, g_O1 + NH * 256, g_M1 + NH * 256, ll);

    // h1 = relu(accO + b1) stays in registers (this IS the 2nd buffer)
    {
      float4 b0 = reinterpret_cast<const float4*>(g_O1b)[2 * ll];
      float4 b1 = reinterpret_cast<const float4*>(g_O1b)[2 * ll + 1];
      const float bb[8] = {b0.x, b0.y, b0.z, b0.w, b1.x, b1.y, b1.z, b1.w};
#pragma unroll
      for (int s = 0; s < 8; ++s)
#pragma unroll
        for (int j = 0; j < 8; ++j)
          accO[s][j] = fmaxf(accO[s][j] + bb[j], 0.f);
    }
    // A <- relu(M1^T x + b) in place (all reads of A done above; per-wave in-order)
    write_relu8(Abuf + go, accM, g_M1b, ll);

    // ---- O2 from h1 registers via ds_bpermute; fold O3 + sigmoid + prod
    zero8(accM);  // reuse as acc2
    {
      const float4* __restrict__ Wp = reinterpret_cast<const float4*>(g_O2) + 2 * ll;
#pragma unroll
      for (int jj = 0; jj < 8; ++jj) {   // h1 rows {src + 32*jj}
#pragma unroll 2
        for (int i2 = 0; i2 < 32; ++i2) {
          const int i = 32 * jj + i2;
          float4 w0 = Wp[i * 64], w1 = Wp[i * 64 + 1];
          const int idx = bpbase + 4 * i2;  // broadcast from own 32-group
          float hv[8];
#pragma unroll
          for (int s = 0; s < 8; ++s)
            hv[s] = __int_as_float(
                __builtin_amdgcn_ds_bpermute(idx, __float_as_int(accO[s][jj])));
          const float wj[8] = {w0.x, w0.y, w0.z, w0.w, w1.x, w1.y, w1.z, w1.w};
#pragma unroll
          for (int s = 0; s < 8; ++s)
#pragma unroll
            for (int j = 0; j < 8; ++j)
              accM[s][j] = fmaf(hv[s], wj[j], accM[s][j]);
        }
      }
    }
    {
      float4 b0 = reinterpret_cast<const float4*>(g_O2b)[2 * ll];
      float4 b1 = reinterpret_cast<const float4*>(g_O2b)[2 * ll + 1];
      float4 o0 = reinterpret_cast<const float4*>(g_O3)[2 * ll];
      float4 o1 = reinterpret_cast<const float4*>(g_O3)[2 * ll + 1];
      const float bb[8] = {b0.x, b0.y, b0.z, b0.w, b1.x, b1.y, b1.z, b1.w};
      const float oo[8] = {o0.x, o0.y, o0.z, o0.w, o1.x, o1.y, o1.z, o1.w};
#pragma unroll
      for (int s = 0; s < 8; ++s) {
        float t = 0.f;
#pragma unroll
        for (int j = 0; j < 8; ++j)
          t = fmaf(fmaxf(accM[s][j] + bb[j], 0.f), oo[j], t);
        t += __shfl_xor(t, 1);
        t += __shfl_xor(t, 2);
        t += __shfl_xor(t, 4);
        t += __shfl_xor(t, 8);
        t += __shfl_xor(t, 16);  // sum within 32-group (masks<32 never cross)
        prod[s] *= 1.f / (1.f + expf(-(t + o3bias)));
      }
    }

    // ---- M2: A -> A (in place)
    zero8(accM);
    gemm8<NH>(accM, Abuf + go, g_M2, ll);
    write_relu8(Abuf + go, accM, g_M2b, ll);

    // ---- M3: A -> A (in place)
    zero8(accM);
    gemm8<NH>(accM, Abuf + go, g_M3, ll);
    write_relu8(Abuf + go, accM, g_M3b, ll);
  }

#pragma unroll
  for (int s = 0; s < 8; ++s)
    if (ll == s) out[n0 + 8 * g + s] = prod[s];
}

extern "C" void kernel_launch(void* const* d_in, const int* in_sizes, int n_in,
                              void* d_out, int out_size, void* d_ws, size_t ws_size,
                              hipStream_t stream) {
  const float* towers    = (const float*)d_in[0];
  const float* aggregate = (const float*)d_in[1];
  const float* M1w = (const float*)d_in[2];
  const float* M1b = (const float*)d_in[3];
  const float* M2w = (const float*)d_in[4];
  const float* M2b = (const float*)d_in[5];
  const float* M3w = (const float*)d_in[6];
  const float* M3b = (const float*)d_in[7];
  const float* O1w = (const float*)d_in[8];
  const float* O1b = (const float*)d_in[9];
  const float* O2w = (const float*)d_in[10];
  const float* O2b = (const float*)d_in[11];
  const float* O3w = (const float*)d_in[12];
  const float* O3b = (const float*)d_in[13];
  float* out = (float*)d_out;

  shuffle_kernel<<<270, 256, 0, stream>>>(M1w, M2w, M3w, O1w, O2w, O3w,
                                          M1b, M2b, M3b, O1b, O2b);

  const int nblocks = out_size / SPW;  // 8192
  topdown_kernel<<<nblocks, 64, 0, stream>>>(towers, aggregate, O3b, out);
}